// Round 13
// baseline (169.987 us; speedup 1.0000x reference)
//
#include <hip/hip_runtime.h>
#include <hip/hip_fp16.h>

// Buckets: 128 consecutive dst nodes (dst>>7). NB = 782 for N=100k.
#define NB_MAX 784
#define CAP    2560      // bucket capacity; mean 2048, +11 sigma
#define CHUNK  8192      // edges per bin block

typedef _Float16 half8 __attribute__((ext_vector_type(8)));
typedef float f32x4_t __attribute__((ext_vector_type(4)));

// ---- FUSED: bin (blocks [0,binb)) || gemm1 MFMA (blocks [binb, ...)) ----
// bin: bucket edges by dst>>7; global atomics only on NB hot counters.
// gemm1: hp[N,64] = fp16(x@W1) UNSCALED (dinv applied per-edge later).
__global__ __launch_bounds__(256) void k_bin_gemm1(
        const int* __restrict__ src, const int* __restrict__ dst,
        int* __restrict__ gcur, int* __restrict__ binned, int nb, int e,
        const float* __restrict__ x, const float* __restrict__ W1,
        __half* __restrict__ hp, int n, int binb) {
    __shared__ __align__(16) char smem[64 * 136 * 2];   // max(17408, 6272)
    const int t = threadIdx.x;

    if (blockIdx.x < binb) {
        // ================= bin half =================
        int* hist = (int*)smem;
        int* curs = hist + NB_MAX;
        const int base = blockIdx.x * CHUNK;
        const int lim = min(CHUNK, e - base);

        for (int i = t; i < NB_MAX; i += 256) hist[i] = 0;
        __syncthreads();

        const int i4lim = lim >> 2;
        for (int i = t; i < i4lim; i += 256) {
            int4 d = ((const int4*)(dst + base))[i];
            atomicAdd(&hist[d.x >> 7], 1);
            atomicAdd(&hist[d.y >> 7], 1);
            atomicAdd(&hist[d.z >> 7], 1);
            atomicAdd(&hist[d.w >> 7], 1);
        }
        for (int i = (i4lim << 2) + t; i < lim; i += 256)
            atomicAdd(&hist[dst[base + i] >> 7], 1);
        __syncthreads();

        for (int b = t; b < nb; b += 256) {
            int h = hist[b];
            curs[b] = h ? atomicAdd(&gcur[b], h) : 0;
        }
        __syncthreads();

        for (int i = t; i < i4lim; i += 256) {
            int4 d = ((const int4*)(dst + base))[i];
            int4 s = ((const int4*)(src + base))[i];
            int o0 = atomicAdd(&curs[d.x >> 7], 1);
            int o1 = atomicAdd(&curs[d.y >> 7], 1);
            int o2 = atomicAdd(&curs[d.z >> 7], 1);
            int o3 = atomicAdd(&curs[d.w >> 7], 1);
            if (o0 < CAP) binned[(size_t)(d.x >> 7) * CAP + o0] = (s.x << 7) | (d.x & 127);
            if (o1 < CAP) binned[(size_t)(d.y >> 7) * CAP + o1] = (s.y << 7) | (d.y & 127);
            if (o2 < CAP) binned[(size_t)(d.z >> 7) * CAP + o2] = (s.z << 7) | (d.z & 127);
            if (o3 < CAP) binned[(size_t)(d.w >> 7) * CAP + o3] = (s.w << 7) | (d.w & 127);
        }
        for (int i = (i4lim << 2) + t; i < lim; i += 256) {
            int d = dst[base + i], s = src[base + i];
            int off = atomicAdd(&curs[d >> 7], 1);
            if (off < CAP) binned[(size_t)(d >> 7) * CAP + off] = (s << 7) | (d & 127);
        }
        return;
    }

    // ================= gemm1 half (MFMA 16x16x32 f16) =================
    // A: row=lane&15, k=(lane>>4)*8+j ; B: col=lane&15, same k
    // D: col=lane&15, row(node)=(lane>>4)*4+reg   [m89-verified]
    _Float16* wt = (_Float16*)smem;   // W1^T [out][k], stride 136

    for (int i = t; i < 128 * 64; i += 256) {
        int k = i >> 6, o = i & 63;
        wt[o * 136 + k] = (_Float16)W1[i];
    }
    __syncthreads();

    const int lane = t & 63;
    const int wid  = t >> 6;
    const int row0 = (blockIdx.x - binb) * 64 + wid * 16;
    const int rA   = lane & 15;
    const int g    = lane >> 4;

    f32x4_t acc0 = {0.f, 0.f, 0.f, 0.f};
    f32x4_t acc1 = {0.f, 0.f, 0.f, 0.f};
    f32x4_t acc2 = {0.f, 0.f, 0.f, 0.f};
    f32x4_t acc3 = {0.f, 0.f, 0.f, 0.f};

    const int arow = min(row0 + rA, n - 1);
    const float* ap0 = x + (size_t)arow * 128 + g * 8;

#pragma unroll
    for (int ks = 0; ks < 4; ++ks) {
        const float* ap = ap0 + ks * 32;
        float4 a0 = *(const float4*)ap;
        float4 a1 = *(const float4*)(ap + 4);
        half8 af;
        af[0] = (_Float16)a0.x; af[1] = (_Float16)a0.y;
        af[2] = (_Float16)a0.z; af[3] = (_Float16)a0.w;
        af[4] = (_Float16)a1.x; af[5] = (_Float16)a1.y;
        af[6] = (_Float16)a1.z; af[7] = (_Float16)a1.w;

        const _Float16* wb = wt + rA * 136 + ks * 32 + g * 8;
        half8 b0 = *(const half8*)(wb);
        half8 b1 = *(const half8*)(wb + 16 * 136);
        half8 b2 = *(const half8*)(wb + 32 * 136);
        half8 b3 = *(const half8*)(wb + 48 * 136);
        acc0 = __builtin_amdgcn_mfma_f32_16x16x32_f16(af, b0, acc0, 0, 0, 0);
        acc1 = __builtin_amdgcn_mfma_f32_16x16x32_f16(af, b1, acc1, 0, 0, 0);
        acc2 = __builtin_amdgcn_mfma_f32_16x16x32_f16(af, b2, acc2, 0, 0, 0);
        acc3 = __builtin_amdgcn_mfma_f32_16x16x32_f16(af, b3, acc3, 0, 0, 0);
    }

    _Float16* hph = (_Float16*)hp;
#pragma unroll
    for (int r = 0; r < 4; ++r) {
        int node = row0 + g * 4 + r;
        if (node >= n) continue;
        _Float16* o = hph + (size_t)node * 64 + rA;
        o[0]  = (_Float16)acc0[r];
        o[16] = (_Float16)acc1[r];
        o[32] = (_Float16)acc2[r];
        o[48] = (_Float16)acc3[r];
    }
}

// ---- phase B: within-bucket counting sort -> csr, rpx, dinv. ----
// Inlined global prefix: each block sums gcur[0..b-1] (L2-hot, <=782 ints).
__global__ __launch_bounds__(256) void k_sort(const int* __restrict__ binned,
                                              const int* __restrict__ gcur,
                                              int* __restrict__ csr,
                                              int* __restrict__ rpx,
                                              float* __restrict__ dinv,
                                              int n, int e) {
    __shared__ int hist[128], offs[128];
    __shared__ int red[256];
    const int t = threadIdx.x;
    const int b = blockIdx.x;

    // global prefix over bucket sizes -> base
    int partial = 0;
    for (int j = t; j < b; j += 256) partial += gcur[j];
    red[t] = partial;
    if (t < 128) hist[t] = 0;
    __syncthreads();
    for (int o = 128; o > 0; o >>= 1) {
        if (t < o) red[t] += red[t + o];
        __syncthreads();
    }
    const int base = red[0];
    if (b == 0 && t == 0) rpx[n] = e;

    int sz = gcur[b];
    if (sz > CAP) sz = CAP;
    const int* bp = binned + (size_t)b * CAP;

    const int i4 = sz >> 2;
    for (int i = t; i < i4; i += 256) {
        int4 p = ((const int4*)bp)[i];
        atomicAdd(&hist[p.x & 127], 1);
        atomicAdd(&hist[p.y & 127], 1);
        atomicAdd(&hist[p.z & 127], 1);
        atomicAdd(&hist[p.w & 127], 1);
    }
    for (int i = (i4 << 2) + t; i < sz; i += 256)
        atomicAdd(&hist[bp[i] & 127], 1);
    __syncthreads();

    if (t < 128) offs[t] = hist[t];
    __syncthreads();
    for (int o = 1; o < 128; o <<= 1) {
        int add = (t < 128 && t >= o) ? offs[t - o] : 0;
        __syncthreads();
        if (t < 128) offs[t] += add;
        __syncthreads();
    }

    if (t < 128) {
        int node = (b << 7) + t;
        if (node < n) {
            rpx[node]  = base + offs[t] - hist[t];
            dinv[node] = rsqrtf(1.0f + (float)hist[t]);
        }
    }
    __syncthreads();
    if (t < 128) hist[t] = offs[t] - hist[t];
    __syncthreads();

    for (int i = t; i < sz; i += 256) {
        int p = bp[i];
        int pos = base + atomicAdd(&hist[p & 127], 1);
        csr[pos] = p >> 7;
    }
}

// ============ gather helpers (fp16 rows, f32 accumulate) ============

union Pk8 { float4 f4; __half2 h2[4]; };

__device__ inline void addrow(float acc[8], float4 v) {
    Pk8 u; u.f4 = v;
#pragma unroll
    for (int j = 0; j < 4; ++j) {
        float2 t = __half22float2(u.h2[j]);
        acc[2 * j]     += t.x;
        acc[2 * j + 1] += t.y;
    }
}

__device__ inline void addrow_s(float acc[8], float4 v, float s) {
    Pk8 u; u.f4 = v;
#pragma unroll
    for (int j = 0; j < 4; ++j) {
        float2 t = __half22float2(u.h2[j]);
        acc[2 * j]     = fmaf(t.x, s, acc[2 * j]);
        acc[2 * j + 1] = fmaf(t.y, s, acc[2 * j + 1]);
    }
}

// ---- FUSED layer-1 aggregate + gemm2: hp2 = fp16( relu(agg1)@W2 * dinv ) ----
// SPLIT-GATHER: 4 passes over the edge list, pass k touches only src in
// quarter k -> hp working set 3.2MB < 4MB L2/XCD -> near-compulsory fetches.
__global__ __launch_bounds__(256) void k_agg1(const int* __restrict__ rpx,
                                              const int* __restrict__ csr,
                                              const __half* __restrict__ hp,
                                              const float* __restrict__ dinv,
                                              const float* __restrict__ b1,
                                              const float* __restrict__ W2,
                                              __half* __restrict__ hp2, int n) {
    __shared__ float w2t[32 * 68];   // W2^T [col][f]
    __shared__ float tl[32 * 68];    // relu rows [node-local][f]
    const int t = threadIdx.x;

    for (int i = t; i < 64 * 32; i += 256) {
        int f = i >> 5, j = i & 31;
        w2t[j * 68 + f] = W2[i];
    }

    const int nl   = t >> 3;                       // 0..31
    const int q    = t & 7;                        // 0..7
    const int node = blockIdx.x * 32 + nl;
    const bool alive = node < n;

    float acc[8];
#pragma unroll
    for (int j = 0; j < 8; ++j) acc[j] = 0.f;

    float di = 0.f;
    if (alive) {
        const float4* hp4 = (const float4*)hp;
        const int start = rpx[node], end = rpx[node + 1];
        di = dinv[node];
        addrow_s(acc, hp4[(size_t)node * 8 + q], di);    // self-loop

#pragma unroll 1
        for (int pass = 0; pass < 4; ++pass) {
            const int lo = (int)(((long long)n * pass) >> 2);
            const int hi = (pass == 3) ? n : (int)(((long long)n * (pass + 1)) >> 2);
            int p = start;
            for (; p + 8 <= end; p += 8) {
                int s[8];
#pragma unroll
                for (int j = 0; j < 8; ++j) s[j] = csr[p + j];
#pragma unroll
                for (int j = 0; j < 8; ++j) {
                    if (s[j] >= lo && s[j] < hi) {
                        float ds = dinv[s[j]];
                        addrow_s(acc, hp4[(size_t)s[j] * 8 + q], ds);
                    }
                }
            }
            for (; p < end; ++p) {
                int s0 = csr[p];
                if (s0 >= lo && s0 < hi)
                    addrow_s(acc, hp4[(size_t)s0 * 8 + q], dinv[s0]);
            }
        }
    }

    // t = relu(acc*di + b1) -> LDS
    float4 ba = ((const float4*)b1)[q * 2];
    float4 bb = ((const float4*)b1)[q * 2 + 1];
    float4 t0, t1;
    t0.x = fmaxf(fmaf(acc[0], di, ba.x), 0.f);
    t0.y = fmaxf(fmaf(acc[1], di, ba.y), 0.f);
    t0.z = fmaxf(fmaf(acc[2], di, ba.z), 0.f);
    t0.w = fmaxf(fmaf(acc[3], di, ba.w), 0.f);
    t1.x = fmaxf(fmaf(acc[4], di, bb.x), 0.f);
    t1.y = fmaxf(fmaf(acc[5], di, bb.y), 0.f);
    t1.z = fmaxf(fmaf(acc[6], di, bb.z), 0.f);
    t1.w = fmaxf(fmaf(acc[7], di, bb.w), 0.f);
    *(float4*)(tl + nl * 68 + q * 8)     = t0;
    *(float4*)(tl + nl * 68 + q * 8 + 4) = t1;
    __syncthreads();

    if (!alive) return;

    const float* trow = tl + nl * 68;
    const float* wa = w2t + q * 68;
    const float* wb = w2t + (q + 8) * 68;
    const float* wc = w2t + (q + 16) * 68;
    const float* wd = w2t + (q + 24) * 68;
    float o0 = 0.f, o1 = 0.f, o2 = 0.f, o3 = 0.f;
#pragma unroll
    for (int f4 = 0; f4 < 16; ++f4) {
        float4 tv = *(const float4*)(trow + f4 * 4);
        float4 v0 = *(const float4*)(wa + f4 * 4);
        float4 v1 = *(const float4*)(wb + f4 * 4);
        float4 v2 = *(const float4*)(wc + f4 * 4);
        float4 v3 = *(const float4*)(wd + f4 * 4);
        o0 += tv.x * v0.x + tv.y * v0.y + tv.z * v0.z + tv.w * v0.w;
        o1 += tv.x * v1.x + tv.y * v1.y + tv.z * v1.z + tv.w * v1.w;
        o2 += tv.x * v2.x + tv.y * v2.y + tv.z * v2.z + tv.w * v2.w;
        o3 += tv.x * v3.x + tv.y * v3.y + tv.z * v3.z + tv.w * v3.w;
    }
    _Float16* hq = (_Float16*)hp2 + (size_t)node * 32;
    hq[q]      = (_Float16)(o0 * di);
    hq[q + 8]  = (_Float16)(o1 * di);
    hq[q + 16] = (_Float16)(o2 * di);
    hq[q + 24] = (_Float16)(o3 * di);
}

// ---- layer-2 aggregate: out = gather(hp2)*dinv + b2, f32 (hp2 pre-scaled) ----
template<int LOGF>
__global__ __launch_bounds__(256) void k_aggregate(const int* __restrict__ rpx,
                                                   const int* __restrict__ csr,
                                                   const __half* __restrict__ hp,
                                                   const float* __restrict__ dinv,
                                                   const float* __restrict__ bias,
                                                   float* __restrict__ out, int n) {
    constexpr int F   = 1 << LOGF;
    constexpr int TPN = F / 8;
    int gid  = blockIdx.x * 256 + threadIdx.x;
    int node = gid / TPN;
    int q    = gid % TPN;
    if (node >= n) return;

    const float4* hp4 = (const float4*)hp;
    int start = rpx[node], end = rpx[node + 1];

    float acc[8];
#pragma unroll
    for (int j = 0; j < 8; ++j) acc[j] = 0.f;
    addrow(acc, hp4[(size_t)node * TPN + q]);

    int p = start;
    for (; p + 8 <= end; p += 8) {
        int s[8];
#pragma unroll
        for (int j = 0; j < 8; ++j) s[j] = csr[p + j];
        float4 v[8];
#pragma unroll
        for (int j = 0; j < 8; ++j) v[j] = hp4[(size_t)s[j] * TPN + q];
#pragma unroll
        for (int j = 0; j < 8; ++j) addrow(acc, v[j]);
    }
    for (; p + 2 <= end; p += 2) {
        int s0 = csr[p], s1 = csr[p + 1];
        float4 v0 = hp4[(size_t)s0 * TPN + q];
        float4 v1 = hp4[(size_t)s1 * TPN + q];
        addrow(acc, v0);
        addrow(acc, v1);
    }
    if (p < end)
        addrow(acc, hp4[(size_t)csr[p] * TPN + q]);

    float di = dinv[node];
    float4 b0 = ((const float4*)bias)[q * 2];
    float4 b1v = ((const float4*)bias)[q * 2 + 1];
    float4 r0, r1;
    r0.x = fmaf(acc[0], di, b0.x); r0.y = fmaf(acc[1], di, b0.y);
    r0.z = fmaf(acc[2], di, b0.z); r0.w = fmaf(acc[3], di, b0.w);
    r1.x = fmaf(acc[4], di, b1v.x); r1.y = fmaf(acc[5], di, b1v.y);
    r1.z = fmaf(acc[6], di, b1v.z); r1.w = fmaf(acc[7], di, b1v.w);
    float4* o4 = (float4*)out;
    o4[(size_t)node * (F / 4) + q * 2]     = r0;
    o4[(size_t)node * (F / 4) + q * 2 + 1] = r1;
}

// ============ launch ============
// ws: gcur[784] | rpx[N+4] | dinv[N] | binned[784*CAP] | csr[E] |
//     hp[64N halves] | hp2[32N halves]   (~34.5 MB)

extern "C" void kernel_launch(void* const* d_in, const int* in_sizes, int n_in,
                              void* d_out, int out_size, void* d_ws, size_t ws_size,
                              hipStream_t stream) {
    const float* x  = (const float*)d_in[0];
    const float* W1 = (const float*)d_in[1];
    const float* b1 = (const float*)d_in[2];
    const float* W2 = (const float*)d_in[3];
    const float* b2 = (const float*)d_in[4];
    const int*   ei = (const int*)d_in[5];

    const int N = in_sizes[0] / 128;
    const int E = in_sizes[5] / 2;
    const int* src = ei;
    const int* dst = ei + E;
    const int NB = (N + 127) >> 7;

    char* w = (char*)d_ws;
    int*    gcur   = (int*)w;                  w += NB_MAX * 4;
    int*    rpx    = (int*)w;                  w += (size_t)(N + 4) * 4;
    float*  dinv   = (float*)w;                w += (size_t)N * 4;
    int*    binned = (int*)w;                  w += (size_t)NB_MAX * CAP * 4;
    int*    csr    = (int*)w;                  w += (size_t)E * 4;
    __half* hp     = (__half*)w;               w += (size_t)N * 64 * 2;
    __half* hp2    = (__half*)w;               w += (size_t)N * 32 * 2;
    float*  out    = (float*)d_out;

    const int binb = (E + CHUNK - 1) / CHUNK;  // 196
    const int gb1  = (N + 63) / 64;            // 1563

    (void)hipMemsetAsync(gcur, 0, NB_MAX * 4, stream);

    // fused: bin (edge bucketing) || gemm1 (hp = fp16(x@W1), unscaled, MFMA)
    k_bin_gemm1<<<binb + gb1, 256, 0, stream>>>(src, dst, gcur, binned, NB, E,
                                                x, W1, hp, N, binb);

    // counting sort (global prefix inlined) -> csr, rpx, dinv
    k_sort<<<NB, 256, 0, stream>>>(binned, gcur, csr, rpx, dinv, N, E);

    // fused: agg1 (4-pass split gather) -> relu -> @W2 -> *dinv -> hp2 (fp16)
    k_agg1<<<(N + 31) / 32, 256, 0, stream>>>(rpx, csr, hp, dinv, b1, W2, hp2, N);

    // layer 2 aggregate: out = gather(hp2)*dinv + b2
    k_aggregate<5><<<(N * 4 + 255) / 256, 256, 0, stream>>>(rpx, csr, hp2, dinv, b2, out, N);
}

// Round 14
// 134.204 us; speedup vs baseline: 1.2666x; 1.2666x over previous
//
#include <hip/hip_runtime.h>
#include <hip/hip_fp16.h>

// Buckets: 128 consecutive dst nodes (dst>>7). NB = 782 for N=100k.
#define NB_MAX 784
#define CAP    2560      // bucket capacity; mean 2048, +11 sigma
#define CHUNK  8192      // edges per bin block

typedef _Float16 half8 __attribute__((ext_vector_type(8)));
typedef float f32x4_t __attribute__((ext_vector_type(4)));

// ---- FUSED: bin (blocks [0,binb)) || gemm1 MFMA (blocks [binb, ...)) ----
__global__ __launch_bounds__(256) void k_bin_gemm1(
        const int* __restrict__ src, const int* __restrict__ dst,
        int* __restrict__ gcur, int* __restrict__ binned, int nb, int e,
        const float* __restrict__ x, const float* __restrict__ W1,
        __half* __restrict__ hp, int n, int binb) {
    __shared__ __align__(16) char smem[64 * 136 * 2];   // max(17408, 6272)
    const int t = threadIdx.x;

    if (blockIdx.x < binb) {
        // ================= bin half =================
        int* hist = (int*)smem;
        int* curs = hist + NB_MAX;
        const int base = blockIdx.x * CHUNK;
        const int lim = min(CHUNK, e - base);

        for (int i = t; i < NB_MAX; i += 256) hist[i] = 0;
        __syncthreads();

        const int i4lim = lim >> 2;
        for (int i = t; i < i4lim; i += 256) {
            int4 d = ((const int4*)(dst + base))[i];
            atomicAdd(&hist[d.x >> 7], 1);
            atomicAdd(&hist[d.y >> 7], 1);
            atomicAdd(&hist[d.z >> 7], 1);
            atomicAdd(&hist[d.w >> 7], 1);
        }
        for (int i = (i4lim << 2) + t; i < lim; i += 256)
            atomicAdd(&hist[dst[base + i] >> 7], 1);
        __syncthreads();

        for (int b = t; b < nb; b += 256) {
            int h = hist[b];
            curs[b] = h ? atomicAdd(&gcur[b], h) : 0;
        }
        __syncthreads();

        for (int i = t; i < i4lim; i += 256) {
            int4 d = ((const int4*)(dst + base))[i];
            int4 s = ((const int4*)(src + base))[i];
            int o0 = atomicAdd(&curs[d.x >> 7], 1);
            int o1 = atomicAdd(&curs[d.y >> 7], 1);
            int o2 = atomicAdd(&curs[d.z >> 7], 1);
            int o3 = atomicAdd(&curs[d.w >> 7], 1);
            if (o0 < CAP) binned[(size_t)(d.x >> 7) * CAP + o0] = (s.x << 7) | (d.x & 127);
            if (o1 < CAP) binned[(size_t)(d.y >> 7) * CAP + o1] = (s.y << 7) | (d.y & 127);
            if (o2 < CAP) binned[(size_t)(d.z >> 7) * CAP + o2] = (s.z << 7) | (d.z & 127);
            if (o3 < CAP) binned[(size_t)(d.w >> 7) * CAP + o3] = (s.w << 7) | (d.w & 127);
        }
        for (int i = (i4lim << 2) + t; i < lim; i += 256) {
            int d = dst[base + i], s = src[base + i];
            int off = atomicAdd(&curs[d >> 7], 1);
            if (off < CAP) binned[(size_t)(d >> 7) * CAP + off] = (s << 7) | (d & 127);
        }
        return;
    }

    // ================= gemm1 half (MFMA 16x16x32 f16) =================
    // A: row=lane&15, k=(lane>>4)*8+j ; B: col=lane&15, same k
    // D: col=lane&15, row(node)=(lane>>4)*4+reg   [m89-verified]
    _Float16* wt = (_Float16*)smem;   // W1^T [out][k], stride 136

    for (int i = t; i < 128 * 64; i += 256) {
        int k = i >> 6, o = i & 63;
        wt[o * 136 + k] = (_Float16)W1[i];
    }
    __syncthreads();

    const int lane = t & 63;
    const int wid  = t >> 6;
    const int row0 = (blockIdx.x - binb) * 64 + wid * 16;
    const int rA   = lane & 15;
    const int g    = lane >> 4;

    f32x4_t acc0 = {0.f, 0.f, 0.f, 0.f};
    f32x4_t acc1 = {0.f, 0.f, 0.f, 0.f};
    f32x4_t acc2 = {0.f, 0.f, 0.f, 0.f};
    f32x4_t acc3 = {0.f, 0.f, 0.f, 0.f};

    const int arow = min(row0 + rA, n - 1);
    const float* ap0 = x + (size_t)arow * 128 + g * 8;

#pragma unroll
    for (int ks = 0; ks < 4; ++ks) {
        const float* ap = ap0 + ks * 32;
        float4 a0 = *(const float4*)ap;
        float4 a1 = *(const float4*)(ap + 4);
        half8 af;
        af[0] = (_Float16)a0.x; af[1] = (_Float16)a0.y;
        af[2] = (_Float16)a0.z; af[3] = (_Float16)a0.w;
        af[4] = (_Float16)a1.x; af[5] = (_Float16)a1.y;
        af[6] = (_Float16)a1.z; af[7] = (_Float16)a1.w;

        const _Float16* wb = wt + rA * 136 + ks * 32 + g * 8;
        half8 b0 = *(const half8*)(wb);
        half8 b1 = *(const half8*)(wb + 16 * 136);
        half8 b2 = *(const half8*)(wb + 32 * 136);
        half8 b3 = *(const half8*)(wb + 48 * 136);
        acc0 = __builtin_amdgcn_mfma_f32_16x16x32_f16(af, b0, acc0, 0, 0, 0);
        acc1 = __builtin_amdgcn_mfma_f32_16x16x32_f16(af, b1, acc1, 0, 0, 0);
        acc2 = __builtin_amdgcn_mfma_f32_16x16x32_f16(af, b2, acc2, 0, 0, 0);
        acc3 = __builtin_amdgcn_mfma_f32_16x16x32_f16(af, b3, acc3, 0, 0, 0);
    }

    _Float16* hph = (_Float16*)hp;
#pragma unroll
    for (int r = 0; r < 4; ++r) {
        int node = row0 + g * 4 + r;
        if (node >= n) continue;
        _Float16* o = hph + (size_t)node * 64 + rA;
        o[0]  = (_Float16)acc0[r];
        o[16] = (_Float16)acc1[r];
        o[32] = (_Float16)acc2[r];
        o[48] = (_Float16)acc3[r];
    }
}

// ---- phase B: 512-key counting sort (dst_local, src_quarter) -> csr, rpx, dinv ----
// csr comes out quarter-ordered per node: the aggregate's sequential walk then
// accesses hp in src-quarter order -> per-XCD L2 working set ~3.2MB.
__global__ __launch_bounds__(256) void k_sort(const int* __restrict__ binned,
                                              const int* __restrict__ gcur,
                                              int* __restrict__ csr,
                                              int* __restrict__ rpx,
                                              float* __restrict__ dinv,
                                              int n, int e, int q1, int q2, int q3) {
    __shared__ int hist[512], offs[512];
    __shared__ int red[256];
    const int t = threadIdx.x;
    const int b = blockIdx.x;

    // global prefix over bucket sizes -> base
    int partial = 0;
    for (int j = t; j < b; j += 256) partial += gcur[j];
    red[t] = partial;
    hist[t] = 0; hist[t + 256] = 0;
    __syncthreads();
    for (int o = 128; o > 0; o >>= 1) {
        if (t < o) red[t] += red[t + o];
        __syncthreads();
    }
    const int base = red[0];
    if (b == 0 && t == 0) rpx[n] = e;

    int sz = gcur[b];
    if (sz > CAP) sz = CAP;
    const int* bp = binned + (size_t)b * CAP;

    for (int i = t; i < sz; i += 256) {
        int p = bp[i];
        int s = p >> 7;
        int k = ((p & 127) << 2) + (s >= q1) + (s >= q2) + (s >= q3);
        atomicAdd(&hist[k], 1);
    }
    __syncthreads();

    offs[t] = hist[t]; offs[t + 256] = hist[t + 256];
    __syncthreads();
    for (int o = 1; o < 512; o <<= 1) {
        int a0 = (t >= o) ? offs[t - o] : 0;
        int a1 = offs[t + 256 - o];          // t+256 >= o always (o <= 256)
        __syncthreads();
        offs[t] += a0;
        offs[t + 256] += a1;
        __syncthreads();
    }

    if (t < 128) {
        int node = (b << 7) + t;
        if (node < n) {
            int deg = hist[4 * t] + hist[4 * t + 1] + hist[4 * t + 2] + hist[4 * t + 3];
            rpx[node]  = base + offs[4 * t] - hist[4 * t];   // start of node's block
            dinv[node] = rsqrtf(1.0f + (float)deg);
        }
    }
    __syncthreads();
    hist[t]       = offs[t]       - hist[t];        // cursors = exclusive scan
    hist[t + 256] = offs[t + 256] - hist[t + 256];
    __syncthreads();

    for (int i = t; i < sz; i += 256) {
        int p = bp[i];
        int s = p >> 7;
        int k = ((p & 127) << 2) + (s >= q1) + (s >= q2) + (s >= q3);
        int pos = base + atomicAdd(&hist[k], 1);
        csr[pos] = s;
    }
}

// ============ gather helpers (fp16 rows, f32 accumulate) ============

union Pk8 { float4 f4; __half2 h2[4]; };

__device__ inline void addrow(float acc[8], float4 v) {
    Pk8 u; u.f4 = v;
#pragma unroll
    for (int j = 0; j < 4; ++j) {
        float2 t = __half22float2(u.h2[j]);
        acc[2 * j]     += t.x;
        acc[2 * j + 1] += t.y;
    }
}

__device__ inline void addrow_s(float acc[8], float4 v, float s) {
    Pk8 u; u.f4 = v;
#pragma unroll
    for (int j = 0; j < 4; ++j) {
        float2 t = __half22float2(u.h2[j]);
        acc[2 * j]     = fmaf(t.x, s, acc[2 * j]);
        acc[2 * j + 1] = fmaf(t.y, s, acc[2 * j + 1]);
    }
}

// ---- FUSED layer-1 aggregate + gemm2: hp2 = fp16( relu(agg1)@W2 * dinv ) ----
// Single-pass 8-deep gather; csr is src-quarter-ordered so hp accesses walk
// 3.2MB L2-sized windows.
__global__ __launch_bounds__(256) void k_agg1(const int* __restrict__ rpx,
                                              const int* __restrict__ csr,
                                              const __half* __restrict__ hp,
                                              const float* __restrict__ dinv,
                                              const float* __restrict__ b1,
                                              const float* __restrict__ W2,
                                              __half* __restrict__ hp2, int n) {
    __shared__ float w2t[32 * 68];   // W2^T [col][f]
    __shared__ float tl[32 * 68];    // relu rows [node-local][f]
    const int t = threadIdx.x;

    for (int i = t; i < 64 * 32; i += 256) {
        int f = i >> 5, j = i & 31;
        w2t[j * 68 + f] = W2[i];
    }

    const int nl   = t >> 3;                       // 0..31
    const int q    = t & 7;                        // 0..7
    const int node = blockIdx.x * 32 + nl;
    const bool alive = node < n;

    float acc[8];
#pragma unroll
    for (int j = 0; j < 8; ++j) acc[j] = 0.f;

    float di = 0.f;
    if (alive) {
        const float4* hp4 = (const float4*)hp;
        int start = rpx[node], end = rpx[node + 1];
        di = dinv[node];
        addrow_s(acc, hp4[(size_t)node * 8 + q], di);    // self-loop

        int p = start;
        for (; p + 8 <= end; p += 8) {
            int s[8];
#pragma unroll
            for (int j = 0; j < 8; ++j) s[j] = csr[p + j];
            float ds[8];
#pragma unroll
            for (int j = 0; j < 8; ++j) ds[j] = dinv[s[j]];
            float4 v[8];
#pragma unroll
            for (int j = 0; j < 8; ++j) v[j] = hp4[(size_t)s[j] * 8 + q];
#pragma unroll
            for (int j = 0; j < 8; ++j) addrow_s(acc, v[j], ds[j]);
        }
        for (; p + 2 <= end; p += 2) {
            int s0 = csr[p], s1 = csr[p + 1];
            float d0 = dinv[s0], d1 = dinv[s1];
            float4 v0 = hp4[(size_t)s0 * 8 + q];
            float4 v1 = hp4[(size_t)s1 * 8 + q];
            addrow_s(acc, v0, d0);
            addrow_s(acc, v1, d1);
        }
        if (p < end) {
            int s0 = csr[p];
            addrow_s(acc, hp4[(size_t)s0 * 8 + q], dinv[s0]);
        }
    }

    // t = relu(acc*di + b1) -> LDS
    float4 ba = ((const float4*)b1)[q * 2];
    float4 bb = ((const float4*)b1)[q * 2 + 1];
    float4 t0, t1;
    t0.x = fmaxf(fmaf(acc[0], di, ba.x), 0.f);
    t0.y = fmaxf(fmaf(acc[1], di, ba.y), 0.f);
    t0.z = fmaxf(fmaf(acc[2], di, ba.z), 0.f);
    t0.w = fmaxf(fmaf(acc[3], di, ba.w), 0.f);
    t1.x = fmaxf(fmaf(acc[4], di, bb.x), 0.f);
    t1.y = fmaxf(fmaf(acc[5], di, bb.y), 0.f);
    t1.z = fmaxf(fmaf(acc[6], di, bb.z), 0.f);
    t1.w = fmaxf(fmaf(acc[7], di, bb.w), 0.f);
    *(float4*)(tl + nl * 68 + q * 8)     = t0;
    *(float4*)(tl + nl * 68 + q * 8 + 4) = t1;
    __syncthreads();

    if (!alive) return;

    const float* trow = tl + nl * 68;
    const float* wa = w2t + q * 68;
    const float* wb = w2t + (q + 8) * 68;
    const float* wc = w2t + (q + 16) * 68;
    const float* wd = w2t + (q + 24) * 68;
    float o0 = 0.f, o1 = 0.f, o2 = 0.f, o3 = 0.f;
#pragma unroll
    for (int f4 = 0; f4 < 16; ++f4) {
        float4 tv = *(const float4*)(trow + f4 * 4);
        float4 v0 = *(const float4*)(wa + f4 * 4);
        float4 v1 = *(const float4*)(wb + f4 * 4);
        float4 v2 = *(const float4*)(wc + f4 * 4);
        float4 v3 = *(const float4*)(wd + f4 * 4);
        o0 += tv.x * v0.x + tv.y * v0.y + tv.z * v0.z + tv.w * v0.w;
        o1 += tv.x * v1.x + tv.y * v1.y + tv.z * v1.z + tv.w * v1.w;
        o2 += tv.x * v2.x + tv.y * v2.y + tv.z * v2.z + tv.w * v2.w;
        o3 += tv.x * v3.x + tv.y * v3.y + tv.z * v3.z + tv.w * v3.w;
    }
    _Float16* hq = (_Float16*)hp2 + (size_t)node * 32;
    hq[q]      = (_Float16)(o0 * di);
    hq[q + 8]  = (_Float16)(o1 * di);
    hq[q + 16] = (_Float16)(o2 * di);
    hq[q + 24] = (_Float16)(o3 * di);
}

// ---- layer-2 aggregate: out = gather(hp2)*dinv + b2, f32 (hp2 pre-scaled) ----
template<int LOGF>
__global__ __launch_bounds__(256) void k_aggregate(const int* __restrict__ rpx,
                                                   const int* __restrict__ csr,
                                                   const __half* __restrict__ hp,
                                                   const float* __restrict__ dinv,
                                                   const float* __restrict__ bias,
                                                   float* __restrict__ out, int n) {
    constexpr int F   = 1 << LOGF;
    constexpr int TPN = F / 8;
    int gid  = blockIdx.x * 256 + threadIdx.x;
    int node = gid / TPN;
    int q    = gid % TPN;
    if (node >= n) return;

    const float4* hp4 = (const float4*)hp;
    int start = rpx[node], end = rpx[node + 1];

    float acc[8];
#pragma unroll
    for (int j = 0; j < 8; ++j) acc[j] = 0.f;
    addrow(acc, hp4[(size_t)node * TPN + q]);

    int p = start;
    for (; p + 8 <= end; p += 8) {
        int s[8];
#pragma unroll
        for (int j = 0; j < 8; ++j) s[j] = csr[p + j];
        float4 v[8];
#pragma unroll
        for (int j = 0; j < 8; ++j) v[j] = hp4[(size_t)s[j] * TPN + q];
#pragma unroll
        for (int j = 0; j < 8; ++j) addrow(acc, v[j]);
    }
    for (; p + 2 <= end; p += 2) {
        int s0 = csr[p], s1 = csr[p + 1];
        float4 v0 = hp4[(size_t)s0 * TPN + q];
        float4 v1 = hp4[(size_t)s1 * TPN + q];
        addrow(acc, v0);
        addrow(acc, v1);
    }
    if (p < end)
        addrow(acc, hp4[(size_t)csr[p] * TPN + q]);

    float di = dinv[node];
    float4 b0 = ((const float4*)bias)[q * 2];
    float4 b1v = ((const float4*)bias)[q * 2 + 1];
    float4 r0, r1;
    r0.x = fmaf(acc[0], di, b0.x); r0.y = fmaf(acc[1], di, b0.y);
    r0.z = fmaf(acc[2], di, b0.z); r0.w = fmaf(acc[3], di, b0.w);
    r1.x = fmaf(acc[4], di, b1v.x); r1.y = fmaf(acc[5], di, b1v.y);
    r1.z = fmaf(acc[6], di, b1v.z); r1.w = fmaf(acc[7], di, b1v.w);
    float4* o4 = (float4*)out;
    o4[(size_t)node * (F / 4) + q * 2]     = r0;
    o4[(size_t)node * (F / 4) + q * 2 + 1] = r1;
}

// ============ launch ============
// ws: gcur[784] | rpx[N+4] | dinv[N] | binned[784*CAP] | csr[E] |
//     hp[64N halves] | hp2[32N halves]   (~34.5 MB)

extern "C" void kernel_launch(void* const* d_in, const int* in_sizes, int n_in,
                              void* d_out, int out_size, void* d_ws, size_t ws_size,
                              hipStream_t stream) {
    const float* x  = (const float*)d_in[0];
    const float* W1 = (const float*)d_in[1];
    const float* b1 = (const float*)d_in[2];
    const float* W2 = (const float*)d_in[3];
    const float* b2 = (const float*)d_in[4];
    const int*   ei = (const int*)d_in[5];

    const int N = in_sizes[0] / 128;
    const int E = in_sizes[5] / 2;
    const int* src = ei;
    const int* dst = ei + E;
    const int NB = (N + 127) >> 7;

    char* w = (char*)d_ws;
    int*    gcur   = (int*)w;                  w += NB_MAX * 4;
    int*    rpx    = (int*)w;                  w += (size_t)(N + 4) * 4;
    float*  dinv   = (float*)w;                w += (size_t)N * 4;
    int*    binned = (int*)w;                  w += (size_t)NB_MAX * CAP * 4;
    int*    csr    = (int*)w;                  w += (size_t)E * 4;
    __half* hp     = (__half*)w;               w += (size_t)N * 64 * 2;
    __half* hp2    = (__half*)w;               w += (size_t)N * 32 * 2;
    float*  out    = (float*)d_out;

    const int binb = (E + CHUNK - 1) / CHUNK;  // 196
    const int gb1  = (N + 63) / 64;            // 1563

    (void)hipMemsetAsync(gcur, 0, NB_MAX * 4, stream);

    // fused: bin (edge bucketing) || gemm1 (hp = fp16(x@W1), unscaled, MFMA)
    k_bin_gemm1<<<binb + gb1, 256, 0, stream>>>(src, dst, gcur, binned, NB, E,
                                                x, W1, hp, N, binb);

    // 512-key counting sort -> csr (src-quarter-ordered), rpx, dinv
    k_sort<<<NB, 256, 0, stream>>>(binned, gcur, csr, rpx, dinv, N, E,
                                   N / 4, N / 2, (3 * N) / 4);

    // fused: agg1 -> relu -> @W2 -> *dinv -> hp2 (fp16)
    k_agg1<<<(N + 31) / 32, 256, 0, stream>>>(rpx, csr, hp, dinv, b1, W2, hp2, N);

    // layer 2 aggregate: out = gather(hp2)*dinv + b2
    k_aggregate<5><<<(N * 4 + 255) / 256, 256, 0, stream>>>(rpx, csr, hp2, dinv, b2, out, N);
}

// Round 15
// 132.627 us; speedup vs baseline: 1.2817x; 1.0119x over previous
//
#include <hip/hip_runtime.h>
#include <hip/hip_fp16.h>

// Buckets: 128 consecutive dst nodes (dst>>7). NB = 782 for N=100k.
#define NB_MAX 784
#define CAP    2560      // bucket capacity; mean 2048, +11 sigma
#define CHUNK  8192      // edges per bin block

typedef _Float16 half8 __attribute__((ext_vector_type(8)));
typedef float f32x4_t __attribute__((ext_vector_type(4)));

// ---- FUSED: bin (blocks [0,binb)) || gemm1 MFMA (blocks [binb, ...)) ----
__global__ __launch_bounds__(256) void k_bin_gemm1(
        const int* __restrict__ src, const int* __restrict__ dst,
        int* __restrict__ gcur, int* __restrict__ binned, int nb, int e,
        const float* __restrict__ x, const float* __restrict__ W1,
        __half* __restrict__ hp, int n, int binb) {
    __shared__ __align__(16) char smem[64 * 136 * 2];   // max(17408, 6272)
    const int t = threadIdx.x;

    if (blockIdx.x < binb) {
        // ================= bin half =================
        int* hist = (int*)smem;
        int* curs = hist + NB_MAX;
        const int base = blockIdx.x * CHUNK;
        const int lim = min(CHUNK, e - base);

        for (int i = t; i < NB_MAX; i += 256) hist[i] = 0;
        __syncthreads();

        const int i4lim = lim >> 2;
        for (int i = t; i < i4lim; i += 256) {
            int4 d = ((const int4*)(dst + base))[i];
            atomicAdd(&hist[d.x >> 7], 1);
            atomicAdd(&hist[d.y >> 7], 1);
            atomicAdd(&hist[d.z >> 7], 1);
            atomicAdd(&hist[d.w >> 7], 1);
        }
        for (int i = (i4lim << 2) + t; i < lim; i += 256)
            atomicAdd(&hist[dst[base + i] >> 7], 1);
        __syncthreads();

        for (int b = t; b < nb; b += 256) {
            int h = hist[b];
            curs[b] = h ? atomicAdd(&gcur[b], h) : 0;
        }
        __syncthreads();

        for (int i = t; i < i4lim; i += 256) {
            int4 d = ((const int4*)(dst + base))[i];
            int4 s = ((const int4*)(src + base))[i];
            int o0 = atomicAdd(&curs[d.x >> 7], 1);
            int o1 = atomicAdd(&curs[d.y >> 7], 1);
            int o2 = atomicAdd(&curs[d.z >> 7], 1);
            int o3 = atomicAdd(&curs[d.w >> 7], 1);
            if (o0 < CAP) binned[(size_t)(d.x >> 7) * CAP + o0] = (s.x << 7) | (d.x & 127);
            if (o1 < CAP) binned[(size_t)(d.y >> 7) * CAP + o1] = (s.y << 7) | (d.y & 127);
            if (o2 < CAP) binned[(size_t)(d.z >> 7) * CAP + o2] = (s.z << 7) | (d.z & 127);
            if (o3 < CAP) binned[(size_t)(d.w >> 7) * CAP + o3] = (s.w << 7) | (d.w & 127);
        }
        for (int i = (i4lim << 2) + t; i < lim; i += 256) {
            int d = dst[base + i], s = src[base + i];
            int off = atomicAdd(&curs[d >> 7], 1);
            if (off < CAP) binned[(size_t)(d >> 7) * CAP + off] = (s << 7) | (d & 127);
        }
        return;
    }

    // ================= gemm1 half (MFMA 16x16x32 f16) =================
    // A: row=lane&15, k=(lane>>4)*8+j ; B: col=lane&15, same k
    // D: col=lane&15, row(node)=(lane>>4)*4+reg   [m89-verified]
    _Float16* wt = (_Float16*)smem;   // W1^T [out][k], stride 136

    for (int i = t; i < 128 * 64; i += 256) {
        int k = i >> 6, o = i & 63;
        wt[o * 136 + k] = (_Float16)W1[i];
    }
    __syncthreads();

    const int lane = t & 63;
    const int wid  = t >> 6;
    const int row0 = (blockIdx.x - binb) * 64 + wid * 16;
    const int rA   = lane & 15;
    const int g    = lane >> 4;

    f32x4_t acc0 = {0.f, 0.f, 0.f, 0.f};
    f32x4_t acc1 = {0.f, 0.f, 0.f, 0.f};
    f32x4_t acc2 = {0.f, 0.f, 0.f, 0.f};
    f32x4_t acc3 = {0.f, 0.f, 0.f, 0.f};

    const int arow = min(row0 + rA, n - 1);
    const float* ap0 = x + (size_t)arow * 128 + g * 8;

#pragma unroll
    for (int ks = 0; ks < 4; ++ks) {
        const float* ap = ap0 + ks * 32;
        float4 a0 = *(const float4*)ap;
        float4 a1 = *(const float4*)(ap + 4);
        half8 af;
        af[0] = (_Float16)a0.x; af[1] = (_Float16)a0.y;
        af[2] = (_Float16)a0.z; af[3] = (_Float16)a0.w;
        af[4] = (_Float16)a1.x; af[5] = (_Float16)a1.y;
        af[6] = (_Float16)a1.z; af[7] = (_Float16)a1.w;

        const _Float16* wb = wt + rA * 136 + ks * 32 + g * 8;
        half8 b0 = *(const half8*)(wb);
        half8 b1 = *(const half8*)(wb + 16 * 136);
        half8 b2 = *(const half8*)(wb + 32 * 136);
        half8 b3 = *(const half8*)(wb + 48 * 136);
        acc0 = __builtin_amdgcn_mfma_f32_16x16x32_f16(af, b0, acc0, 0, 0, 0);
        acc1 = __builtin_amdgcn_mfma_f32_16x16x32_f16(af, b1, acc1, 0, 0, 0);
        acc2 = __builtin_amdgcn_mfma_f32_16x16x32_f16(af, b2, acc2, 0, 0, 0);
        acc3 = __builtin_amdgcn_mfma_f32_16x16x32_f16(af, b3, acc3, 0, 0, 0);
    }

    _Float16* hph = (_Float16*)hp;
#pragma unroll
    for (int r = 0; r < 4; ++r) {
        int node = row0 + g * 4 + r;
        if (node >= n) continue;
        _Float16* o = hph + (size_t)node * 64 + rA;
        o[0]  = (_Float16)acc0[r];
        o[16] = (_Float16)acc1[r];
        o[32] = (_Float16)acc2[r];
        o[48] = (_Float16)acc3[r];
    }
}

// ============ fp16 pack/unpack helpers ============

union Pk8 { float4 f4; __half2 h2[4]; };

__device__ inline void addrow(float acc[8], float4 v) {
    Pk8 u; u.f4 = v;
#pragma unroll
    for (int j = 0; j < 4; ++j) {
        float2 t = __half22float2(u.h2[j]);
        acc[2 * j]     += t.x;
        acc[2 * j + 1] += t.y;
    }
}

// ---- phase B: 128-key counting sort -> csr, rpx, dinv; then scale hp rows ----
// Block b owns nodes [128b, 128b+128): computes their dinv in-block, so it can
// also apply hp[node] *= dinv[node] (16KB r/w, L2-warm) — removing the per-edge
// dinv gather from the aggregate kernels entirely.
__global__ __launch_bounds__(256) void k_sort(const int* __restrict__ binned,
                                              const int* __restrict__ gcur,
                                              int* __restrict__ csr,
                                              int* __restrict__ rpx,
                                              float* __restrict__ dinv,
                                              __half* __restrict__ hp,
                                              int n, int e) {
    __shared__ int hist[128], offs[128];
    __shared__ int red[256];
    __shared__ float dv[128];
    const int t = threadIdx.x;
    const int b = blockIdx.x;

    // global prefix over bucket sizes -> base
    int partial = 0;
    for (int j = t; j < b; j += 256) partial += gcur[j];
    red[t] = partial;
    if (t < 128) hist[t] = 0;
    __syncthreads();
    for (int o = 128; o > 0; o >>= 1) {
        if (t < o) red[t] += red[t + o];
        __syncthreads();
    }
    const int base = red[0];
    if (b == 0 && t == 0) rpx[n] = e;

    int sz = gcur[b];
    if (sz > CAP) sz = CAP;
    const int* bp = binned + (size_t)b * CAP;

    const int i4 = sz >> 2;
    for (int i = t; i < i4; i += 256) {
        int4 p = ((const int4*)bp)[i];
        atomicAdd(&hist[p.x & 127], 1);
        atomicAdd(&hist[p.y & 127], 1);
        atomicAdd(&hist[p.z & 127], 1);
        atomicAdd(&hist[p.w & 127], 1);
    }
    for (int i = (i4 << 2) + t; i < sz; i += 256)
        atomicAdd(&hist[bp[i] & 127], 1);
    __syncthreads();

    if (t < 128) offs[t] = hist[t];
    __syncthreads();
    for (int o = 1; o < 128; o <<= 1) {
        int add = (t < 128 && t >= o) ? offs[t - o] : 0;
        __syncthreads();
        if (t < 128) offs[t] += add;
        __syncthreads();
    }

    if (t < 128) {
        int node = (b << 7) + t;
        float d = 0.f;
        if (node < n) {
            rpx[node] = base + offs[t] - hist[t];
            d = rsqrtf(1.0f + (float)hist[t]);
            dinv[node] = d;
        }
        dv[t] = d;
    }
    __syncthreads();
    if (t < 128) hist[t] = offs[t] - hist[t];   // cursors = exclusive scan
    __syncthreads();

    for (int i = t; i < sz; i += 256) {
        int p = bp[i];
        int pos = base + atomicAdd(&hist[p & 127], 1);
        csr[pos] = p >> 7;
    }

    // scale this bucket's hp rows: hp[node] *= dinv[node]  (8 float4s per row)
    const int node0 = b << 7;
    float4* hp4 = (float4*)hp + (size_t)node0 * 8;
#pragma unroll 1
    for (int idx = t; idx < 128 * 8; idx += 256) {
        int row = idx >> 3;
        if (node0 + row < n) {
            float d = dv[row];
            Pk8 u; u.f4 = hp4[idx];
#pragma unroll
            for (int j = 0; j < 4; ++j) {
                float2 w = __half22float2(u.h2[j]);
                u.h2[j] = __floats2half2_rn(w.x * d, w.y * d);
            }
            hp4[idx] = u.f4;
        }
    }
}

// ---- FUSED layer-1 aggregate + gemm2: hp2 = fp16( relu(agg1)@W2 * dinv ) ----
// hp rows are pre-scaled by dinv[src] (done in k_sort): plain gather-add.
__global__ __launch_bounds__(256) void k_agg1(const int* __restrict__ rpx,
                                              const int* __restrict__ csr,
                                              const __half* __restrict__ hp,
                                              const float* __restrict__ dinv,
                                              const float* __restrict__ b1,
                                              const float* __restrict__ W2,
                                              __half* __restrict__ hp2, int n) {
    __shared__ float w2t[32 * 68];   // W2^T [col][f]
    __shared__ float tl[32 * 68];    // relu rows [node-local][f]
    const int t = threadIdx.x;

    for (int i = t; i < 64 * 32; i += 256) {
        int f = i >> 5, j = i & 31;
        w2t[j * 68 + f] = W2[i];
    }

    const int nl   = t >> 3;                       // 0..31
    const int q    = t & 7;                        // 0..7
    const int node = blockIdx.x * 32 + nl;
    const bool alive = node < n;

    float acc[8];
#pragma unroll
    for (int j = 0; j < 8; ++j) acc[j] = 0.f;

    float di = 0.f;
    if (alive) {
        const float4* hp4 = (const float4*)hp;
        int start = rpx[node], end = rpx[node + 1];
        di = dinv[node];
        addrow(acc, hp4[(size_t)node * 8 + q]);    // self-loop (pre-scaled)

        int p = start;
        for (; p + 8 <= end; p += 8) {
            int s[8];
#pragma unroll
            for (int j = 0; j < 8; ++j) s[j] = csr[p + j];
            float4 v[8];
#pragma unroll
            for (int j = 0; j < 8; ++j) v[j] = hp4[(size_t)s[j] * 8 + q];
#pragma unroll
            for (int j = 0; j < 8; ++j) addrow(acc, v[j]);
        }
        for (; p + 2 <= end; p += 2) {
            int s0 = csr[p], s1 = csr[p + 1];
            float4 v0 = hp4[(size_t)s0 * 8 + q];
            float4 v1 = hp4[(size_t)s1 * 8 + q];
            addrow(acc, v0);
            addrow(acc, v1);
        }
        if (p < end)
            addrow(acc, hp4[(size_t)csr[p] * 8 + q]);
    }

    // t = relu(acc*di + b1) -> LDS
    float4 ba = ((const float4*)b1)[q * 2];
    float4 bb = ((const float4*)b1)[q * 2 + 1];
    float4 t0, t1;
    t0.x = fmaxf(fmaf(acc[0], di, ba.x), 0.f);
    t0.y = fmaxf(fmaf(acc[1], di, ba.y), 0.f);
    t0.z = fmaxf(fmaf(acc[2], di, ba.z), 0.f);
    t0.w = fmaxf(fmaf(acc[3], di, ba.w), 0.f);
    t1.x = fmaxf(fmaf(acc[4], di, bb.x), 0.f);
    t1.y = fmaxf(fmaf(acc[5], di, bb.y), 0.f);
    t1.z = fmaxf(fmaf(acc[6], di, bb.z), 0.f);
    t1.w = fmaxf(fmaf(acc[7], di, bb.w), 0.f);
    *(float4*)(tl + nl * 68 + q * 8)     = t0;
    *(float4*)(tl + nl * 68 + q * 8 + 4) = t1;
    __syncthreads();

    if (!alive) return;

    const float* trow = tl + nl * 68;
    const float* wa = w2t + q * 68;
    const float* wb = w2t + (q + 8) * 68;
    const float* wc = w2t + (q + 16) * 68;
    const float* wd = w2t + (q + 24) * 68;
    float o0 = 0.f, o1 = 0.f, o2 = 0.f, o3 = 0.f;
#pragma unroll
    for (int f4 = 0; f4 < 16; ++f4) {
        float4 tv = *(const float4*)(trow + f4 * 4);
        float4 v0 = *(const float4*)(wa + f4 * 4);
        float4 v1 = *(const float4*)(wb + f4 * 4);
        float4 v2 = *(const float4*)(wc + f4 * 4);
        float4 v3 = *(const float4*)(wd + f4 * 4);
        o0 += tv.x * v0.x + tv.y * v0.y + tv.z * v0.z + tv.w * v0.w;
        o1 += tv.x * v1.x + tv.y * v1.y + tv.z * v1.z + tv.w * v1.w;
        o2 += tv.x * v2.x + tv.y * v2.y + tv.z * v2.z + tv.w * v2.w;
        o3 += tv.x * v3.x + tv.y * v3.y + tv.z * v3.z + tv.w * v3.w;
    }
    _Float16* hq = (_Float16*)hp2 + (size_t)node * 32;
    hq[q]      = (_Float16)(o0 * di);
    hq[q + 8]  = (_Float16)(o1 * di);
    hq[q + 16] = (_Float16)(o2 * di);
    hq[q + 24] = (_Float16)(o3 * di);
}

// ---- layer-2 aggregate: out = gather(hp2)*dinv + b2, f32 (hp2 pre-scaled) ----
template<int LOGF>
__global__ __launch_bounds__(256) void k_aggregate(const int* __restrict__ rpx,
                                                   const int* __restrict__ csr,
                                                   const __half* __restrict__ hp,
                                                   const float* __restrict__ dinv,
                                                   const float* __restrict__ bias,
                                                   float* __restrict__ out, int n) {
    constexpr int F   = 1 << LOGF;
    constexpr int TPN = F / 8;
    int gid  = blockIdx.x * 256 + threadIdx.x;
    int node = gid / TPN;
    int q    = gid % TPN;
    if (node >= n) return;

    const float4* hp4 = (const float4*)hp;
    int start = rpx[node], end = rpx[node + 1];

    float acc[8];
#pragma unroll
    for (int j = 0; j < 8; ++j) acc[j] = 0.f;
    addrow(acc, hp4[(size_t)node * TPN + q]);

    int p = start;
    for (; p + 8 <= end; p += 8) {
        int s[8];
#pragma unroll
        for (int j = 0; j < 8; ++j) s[j] = csr[p + j];
        float4 v[8];
#pragma unroll
        for (int j = 0; j < 8; ++j) v[j] = hp4[(size_t)s[j] * TPN + q];
#pragma unroll
        for (int j = 0; j < 8; ++j) addrow(acc, v[j]);
    }
    for (; p + 2 <= end; p += 2) {
        int s0 = csr[p], s1 = csr[p + 1];
        float4 v0 = hp4[(size_t)s0 * TPN + q];
        float4 v1 = hp4[(size_t)s1 * TPN + q];
        addrow(acc, v0);
        addrow(acc, v1);
    }
    if (p < end)
        addrow(acc, hp4[(size_t)csr[p] * TPN + q]);

    float di = dinv[node];
    float4 b0 = ((const float4*)bias)[q * 2];
    float4 b1v = ((const float4*)bias)[q * 2 + 1];
    float4 r0, r1;
    r0.x = fmaf(acc[0], di, b0.x); r0.y = fmaf(acc[1], di, b0.y);
    r0.z = fmaf(acc[2], di, b0.z); r0.w = fmaf(acc[3], di, b0.w);
    r1.x = fmaf(acc[4], di, b1v.x); r1.y = fmaf(acc[5], di, b1v.y);
    r1.z = fmaf(acc[6], di, b1v.z); r1.w = fmaf(acc[7], di, b1v.w);
    float4* o4 = (float4*)out;
    o4[(size_t)node * (F / 4) + q * 2]     = r0;
    o4[(size_t)node * (F / 4) + q * 2 + 1] = r1;
}

// ============ launch ============
// ws: gcur[784] | rpx[N+4] | dinv[N] | binned[784*CAP] | csr[E] |
//     hp[64N halves] | hp2[32N halves]   (~34.5 MB)

extern "C" void kernel_launch(void* const* d_in, const int* in_sizes, int n_in,
                              void* d_out, int out_size, void* d_ws, size_t ws_size,
                              hipStream_t stream) {
    const float* x  = (const float*)d_in[0];
    const float* W1 = (const float*)d_in[1];
    const float* b1 = (const float*)d_in[2];
    const float* W2 = (const float*)d_in[3];
    const float* b2 = (const float*)d_in[4];
    const int*   ei = (const int*)d_in[5];

    const int N = in_sizes[0] / 128;
    const int E = in_sizes[5] / 2;
    const int* src = ei;
    const int* dst = ei + E;
    const int NB = (N + 127) >> 7;

    char* w = (char*)d_ws;
    int*    gcur   = (int*)w;                  w += NB_MAX * 4;
    int*    rpx    = (int*)w;                  w += (size_t)(N + 4) * 4;
    float*  dinv   = (float*)w;                w += (size_t)N * 4;
    int*    binned = (int*)w;                  w += (size_t)NB_MAX * CAP * 4;
    int*    csr    = (int*)w;                  w += (size_t)E * 4;
    __half* hp     = (__half*)w;               w += (size_t)N * 64 * 2;
    __half* hp2    = (__half*)w;               w += (size_t)N * 32 * 2;
    float*  out    = (float*)d_out;

    const int binb = (E + CHUNK - 1) / CHUNK;  // 196
    const int gb1  = (N + 63) / 64;            // 1563

    (void)hipMemsetAsync(gcur, 0, NB_MAX * 4, stream);

    // fused: bin (edge bucketing) || gemm1 (hp = fp16(x@W1), unscaled, MFMA)
    k_bin_gemm1<<<binb + gb1, 256, 0, stream>>>(src, dst, gcur, binned, NB, E,
                                                x, W1, hp, N, binb);

    // counting sort -> csr, rpx, dinv; then hp[node] *= dinv[node] in-block
    k_sort<<<NB, 256, 0, stream>>>(binned, gcur, csr, rpx, dinv, hp, N, E);

    // fused: agg1 (plain gather, pre-scaled hp) -> relu -> @W2 -> *dinv -> hp2
    k_agg1<<<(N + 31) / 32, 256, 0, stream>>>(rpx, csr, hp, dinv, b1, W2, hp2, N);

    // layer 2 aggregate: out = gather(hp2)*dinv + b2
    k_aggregate<5><<<(N * 4 + 255) / 256, 256, 0, stream>>>(rpx, csr, hp2, dinv, b2, out, N);
}